// Round 1
// baseline (229.855 us; speedup 1.0000x reference)
//
#include <hip/hip_runtime.h>
#include <cstdint>
#include <cstddef>

// SLSTM cell, B=4096 IN=1024 HID=2048 GATE=8192, NH=8 HS=256.
// Plan: cast x,h -> bf16; pack [W_i ; blockdiag(W_h)] transposed (k-contiguous);
// fused bf16-MFMA GEMM (K=1280) computing all 4 gates per block + gate epilogue.

typedef unsigned short u16;
typedef unsigned int   u32;
typedef __bf16 bf16x8 __attribute__((ext_vector_type(8)));
typedef float  f32x4  __attribute__((ext_vector_type(4)));

__device__ __forceinline__ u16 f2bf(float f) {
  u32 u = __builtin_bit_cast(u32, f);
  u32 r = (u + 0x7fffu + ((u >> 16) & 1u)) >> 16;   // RNE
  return (u16)r;
}

__device__ __forceinline__ void gll16(const void* g, void* l) {
  // global -> LDS direct, 16B per lane. LDS dest is wave-uniform base + lane*16.
  __builtin_amdgcn_global_load_lds(
      (__attribute__((address_space(1))) void*)(uintptr_t)g,
      (__attribute__((address_space(3))) void*)l, 16, 0, 0);
}

// ---------------- cast f32 -> bf16, 8 elems/thread ----------------
__global__ void cast_bf16_kernel(const float* __restrict__ src, u16* __restrict__ dst, int n8) {
  int i = blockIdx.x * blockDim.x + threadIdx.x;
  if (i >= n8) return;
  const float4* s = reinterpret_cast<const float4*>(src) + (size_t)i * 2;
  float4 a = s[0], b = s[1];
  union { u16 h[8]; uint4 v; } o;
  o.h[0] = f2bf(a.x); o.h[1] = f2bf(a.y); o.h[2] = f2bf(a.z); o.h[3] = f2bf(a.w);
  o.h[4] = f2bf(b.x); o.h[5] = f2bf(b.y); o.h[6] = f2bf(b.z); o.h[7] = f2bf(b.w);
  reinterpret_cast<uint4*>(dst)[i] = o.v;
}

// ---------------- pack W transposed: WpackT[g][r], g<8192, r<1280 ----------------
// r<1024: W_i[r][g]; r>=1024: W_h[g>>10][r-1024][g&1023]
__global__ void pack_w_kernel(const float* __restrict__ Wi, const float* __restrict__ Wh,
                              u16* __restrict__ Wt) {
  __shared__ u16 tile[64][65];
  const int g0 = blockIdx.x * 64;
  const int r0 = blockIdx.y * 64;
  const int tx = threadIdx.x;   // 0..63 (g in read phase, r in write phase)
  const int ty = threadIdx.y;   // 0..15
  #pragma unroll
  for (int i = 0; i < 4; ++i) {
    const int rr = ty + 16 * i;
    const int r = r0 + rr;
    const int g = g0 + tx;
    float v;
    if (r < 1024) v = Wi[(size_t)r * 8192 + g];
    else {
      const int head = g >> 10;
      v = Wh[(size_t)(head * 256 + (r - 1024)) * 1024 + (g & 1023)];
    }
    tile[rr][tx] = f2bf(v);
  }
  __syncthreads();
  #pragma unroll
  for (int i = 0; i < 4; ++i) {
    const int gg = ty + 16 * i;
    Wt[(size_t)(g0 + gg) * 1280 + r0 + tx] = tile[tx][gg];
  }
}

// ---------------- fused GEMM (K=1280) + gate epilogue ----------------
// grid (32,32): blockIdx.x -> 128-row tile, blockIdx.y -> 64-wide j tile (j in [0,2048)).
// Each block computes pre[:, q*2048 + j] for q=0..3 and fuses the sLSTM gates.
__global__ __launch_bounds__(512) void slstm_main(
    const u16* __restrict__ xb, const u16* __restrict__ hb, const u16* __restrict__ Wt,
    const float* __restrict__ b_i, const float* __restrict__ b_h,
    const float* __restrict__ c_in, const float* __restrict__ m_in, const float* __restrict__ n_in,
    float* __restrict__ out)
{
  __shared__ __align__(16) u16 As[128 * 64];     // A tile, [row][kk], kchunk XOR-swizzled
  __shared__ __align__(16) u16 Bs[4][64 * 64];   // per-gate W^T tile, [col][kk], swizzled

  const int tid  = threadIdx.x;
  const int lane = tid & 63;
  const int w    = tid >> 6;         // wave 0..7, owns rows [w*16, w*16+16)
  const int row0 = blockIdx.x * 128;
  const int j0   = blockIdx.y * 64;
  const int qw   = w >> 1;           // gate this wave stages B for
  const int hh   = w & 1;

  f32x4 acc[4][4];
  #pragma unroll
  for (int q = 0; q < 4; ++q)
    #pragma unroll
    for (int cf = 0; cf < 4; ++cf)
      acc[q][cf] = f32x4{0.0f, 0.0f, 0.0f, 0.0f};

  // --- staging address precompute ---
  int abase[2]; int aoff_x[2]; int aoff_h[2];
  #pragma unroll
  for (int t = 0; t < 2; ++t) {
    const int bu = w * 128 + t * 64;           // 16B-unit base (wave-uniform)
    const int o  = bu + lane;
    const int ar  = o >> 3;                    // row 0..127
    const int akc = (o & 7) ^ (ar & 7);        // pre-swizzled source k-chunk
    abase[t]  = bu * 8;
    aoff_x[t] = (row0 + ar) * 1024 + akc * 8;
    aoff_h[t] = (row0 + ar) * 2048 + akc * 8;
  }
  size_t boff[4]; int bbase[4];
  #pragma unroll
  for (int t = 0; t < 4; ++t) {
    const int bu = hh * 256 + t * 64;
    const int o  = bu + lane;
    const int bc  = o >> 3;                    // col 0..63
    const int bkc = (o & 7) ^ (bc & 7);
    bbase[t] = bu * 8;
    boff[t]  = (size_t)(qw * 2048 + j0 + bc) * 1280 + bkc * 8;
  }
  // h-phase B staging (all 8 waves fill Bs[0])
  const int bu_h = w * 64;
  const int o_h  = bu_h + lane;
  const int bc_h  = o_h >> 3;
  const int bkc_h = (o_h & 7) ^ (bc_h & 7);
  const size_t bhoff = (size_t)(j0 + bc_h) * 1280 + 1024 + bkc_h * 8;
  const int bhbase = bu_h * 8;

  // --- fragment read offsets (swizzled) ---
  int aread[2]; int bread[2][4];
  {
    const int row = w * 16 + (lane & 15);
    #pragma unroll
    for (int s = 0; s < 2; ++s)
      aread[s] = row * 64 + (((s * 4 + (lane >> 4)) ^ (row & 7)) << 3);
    #pragma unroll
    for (int cf = 0; cf < 4; ++cf) {
      const int col = cf * 16 + (lane & 15);
      #pragma unroll
      for (int s = 0; s < 2; ++s)
        bread[s][cf] = col * 64 + (((s * 4 + (lane >> 4)) ^ (col & 7)) << 3);
    }
  }

  // ---- x-phase: K = 0..1024, A tile shared by all 4 gates ----
  for (int ks = 0; ks < 16; ++ks) {
    const int k0 = ks * 64;
    #pragma unroll
    for (int t = 0; t < 2; ++t)
      gll16(xb + aoff_x[t] + k0, (u16*)As + abase[t]);
    #pragma unroll
    for (int t = 0; t < 4; ++t)
      gll16(Wt + boff[t] + k0, &Bs[qw][bbase[t]]);
    __syncthreads();
    #pragma unroll
    for (int s = 0; s < 2; ++s) {
      const bf16x8 a = *(const bf16x8*)((u16*)As + aread[s]);
      #pragma unroll
      for (int q = 0; q < 4; ++q) {
        #pragma unroll
        for (int cf = 0; cf < 4; ++cf) {
          const bf16x8 b = *(const bf16x8*)(&Bs[q][bread[s][cf]]);
          acc[q][cf] = __builtin_amdgcn_mfma_f32_16x16x32_bf16(a, b, acc[q][cf], 0, 0, 0);
        }
      }
    }
    __syncthreads();
  }

  // ---- h-phase: K = 1024..1280; per-gate head slice of h ----
  const int jh = (j0 >= 1024) ? 1 : 0;
  #pragma unroll
  for (int q = 0; q < 4; ++q) {
    const int headq = q * 2 + jh;
    const u16* hsrc = hb + headq * 256;
    for (int ks = 0; ks < 4; ++ks) {
      const int k0h = ks * 64;
      #pragma unroll
      for (int t = 0; t < 2; ++t)
        gll16(hsrc + aoff_h[t] + k0h, (u16*)As + abase[t]);
      gll16(Wt + bhoff + (size_t)q * 2048 * 1280 + k0h, &Bs[0][bhbase]);
      __syncthreads();
      #pragma unroll
      for (int s = 0; s < 2; ++s) {
        const bf16x8 a = *(const bf16x8*)((u16*)As + aread[s]);
        #pragma unroll
        for (int cf = 0; cf < 4; ++cf) {
          const bf16x8 b = *(const bf16x8*)(&Bs[0][bread[s][cf]]);
          acc[q][cf] = __builtin_amdgcn_mfma_f32_16x16x32_bf16(a, b, acc[q][cf], 0, 0, 0);
        }
      }
      __syncthreads();
    }
  }

  // ---- epilogue: gates + state update ----
  // C layout (16x16x32): col = lane&15, row = (lane>>4)*4 + reg  [m89-verified]
  const int lr = (lane >> 4) * 4;
  const int lc = lane & 15;
  #pragma unroll
  for (int cf = 0; cf < 4; ++cf) {
    const int gj = j0 + cf * 16 + lc;          // j in [0,2048)
    const float bias0 = b_i[gj]        + b_h[gj];
    const float bias1 = b_i[2048 + gj] + b_h[2048 + gj];
    const float bias2 = b_i[4096 + gj] + b_h[4096 + gj];
    const float bias3 = b_i[6144 + gj] + b_h[6144 + gj];
    #pragma unroll
    for (int r = 0; r < 4; ++r) {
      const int gb = row0 + w * 16 + lr + r;
      const size_t idx = (size_t)gb * 2048 + gj;
      const float it = acc[0][cf][r] + bias0;
      const float ft = acc[1][cf][r] + bias1;
      const float zt = acc[2][cf][r] + bias2;
      const float ot = acc[3][cf][r] + bias3;
      const float mv = m_in[idx], cv = c_in[idx], nv = n_in[idx];
      const float mn = fmaxf(ft + mv, it);
      const float iv = __expf(it - mn);
      const float fv = __expf(ft - mn + mv);
      const float az = fabsf(zt);
      const float e2 = __expf(-2.0f * az);
      const float tz = (1.0f - e2) / (1.0f + e2);
      const float zv = (zt >= 0.0f) ? tz : -tz;
      const float ov = 1.0f / (1.0f + __expf(-ot));
      const float cn = fv * cv + iv * zv;
      const float nn = fv * nv + iv;
      const float hn = ov * (cn / nn);
      out[idx]            = hn;                 // h_next
      out[ 8388608 + idx] = cn;                 // c_next
      out[16777216 + idx] = mn;                 // m_next
      out[25165824 + idx] = nn;                 // n_next
    }
  }
}

extern "C" void kernel_launch(void* const* d_in, const int* in_sizes, int n_in,
                              void* d_out, int out_size, void* d_ws, size_t ws_size,
                              hipStream_t stream) {
  (void)in_sizes; (void)n_in; (void)out_size; (void)ws_size;
  const float* x  = (const float*)d_in[0];
  const float* h  = (const float*)d_in[1];
  const float* c  = (const float*)d_in[2];
  const float* m  = (const float*)d_in[3];
  const float* n  = (const float*)d_in[4];
  const float* Wi = (const float*)d_in[5];
  const float* bi = (const float*)d_in[6];
  const float* Wh = (const float*)d_in[7];
  const float* bh = (const float*)d_in[8];
  float* out = (float*)d_out;

  // workspace layout (bf16): WpackT 8192x1280 | xb 4096x1024 | hb 4096x2048  (~46.1 MB)
  u16* Wt = (u16*)d_ws;
  u16* xb = Wt + (size_t)8192 * 1280;
  u16* hb = xb + (size_t)4096 * 1024;

  cast_bf16_kernel<<<2048, 256, 0, stream>>>(x, xb, 4096 * 1024 / 8);
  cast_bf16_kernel<<<4096, 256, 0, stream>>>(h, hb, 4096 * 2048 / 8);
  pack_w_kernel<<<dim3(128, 20), dim3(64, 16), 0, stream>>>(Wi, Wh, Wt);
  slstm_main<<<dim3(32, 32), 512, 0, stream>>>(xb, hb, Wt, bi, bh, c, m, n, out);
}

// Round 2
// 173.782 us; speedup vs baseline: 1.3227x; 1.3227x over previous
//
#include <hip/hip_runtime.h>
#include <cstdint>
#include <cstddef>

// SLSTM cell, B=4096 IN=1024 HID=2048 GATE=8192, NH=8 HS=256.
// v2: 256x(64j x 4gate) tile, BK=64, double-buffered LDS (128KB), 2-phase
// prefetch pipeline (stage t+1 before compute t, one barrier/step), merged
// h-phase, setprio around MFMA, XCD-aware block swizzle.

typedef unsigned short u16;
typedef unsigned int   u32;
typedef __bf16 bf16x8 __attribute__((ext_vector_type(8)));
typedef float  f32x4  __attribute__((ext_vector_type(4)));

__device__ __forceinline__ u16 f2bf(float f) {
  u32 u = __builtin_bit_cast(u32, f);
  u32 r = (u + 0x7fffu + ((u >> 16) & 1u)) >> 16;   // RNE
  return (u16)r;
}

__device__ __forceinline__ void gll16(const void* g, void* l) {
  __builtin_amdgcn_global_load_lds(
      (__attribute__((address_space(1))) void*)(uintptr_t)g,
      (__attribute__((address_space(3))) void*)l, 16, 0, 0);
}

// ---------------- cast f32 -> bf16, 8 elems/thread ----------------
__global__ void cast_bf16_kernel(const float* __restrict__ src, u16* __restrict__ dst, int n8) {
  int i = blockIdx.x * blockDim.x + threadIdx.x;
  if (i >= n8) return;
  const float4* s = reinterpret_cast<const float4*>(src) + (size_t)i * 2;
  float4 a = s[0], b = s[1];
  union { u16 h[8]; uint4 v; } o;
  o.h[0] = f2bf(a.x); o.h[1] = f2bf(a.y); o.h[2] = f2bf(a.z); o.h[3] = f2bf(a.w);
  o.h[4] = f2bf(b.x); o.h[5] = f2bf(b.y); o.h[6] = f2bf(b.z); o.h[7] = f2bf(b.w);
  reinterpret_cast<uint4*>(dst)[i] = o.v;
}

// ---------------- pack W transposed: WpackT[g][r], g<8192, r<1280 ----------------
__global__ void pack_w_kernel(const float* __restrict__ Wi, const float* __restrict__ Wh,
                              u16* __restrict__ Wt) {
  __shared__ u16 tile[64][65];
  const int g0 = blockIdx.x * 64;
  const int r0 = blockIdx.y * 64;
  const int tx = threadIdx.x;
  const int ty = threadIdx.y;
  #pragma unroll
  for (int i = 0; i < 4; ++i) {
    const int rr = ty + 16 * i;
    const int r = r0 + rr;
    const int g = g0 + tx;
    float v;
    if (r < 1024) v = Wi[(size_t)r * 8192 + g];
    else {
      const int head = g >> 10;
      v = Wh[(size_t)(head * 256 + (r - 1024)) * 1024 + (g & 1023)];
    }
    tile[rr][tx] = f2bf(v);
  }
  __syncthreads();
  #pragma unroll
  for (int i = 0; i < 4; ++i) {
    const int gg = ty + 16 * i;
    Wt[(size_t)(g0 + gg) * 1280 + r0 + tx] = tile[tx][gg];
  }
}

// ---------------- fused GEMM (K=1280) + gate epilogue ----------------
// 512 blocks: 16 row-blocks (256 rows) x 32 j-blocks (64 j, x4 gates).
// 8 waves: wave (wr=w>>2, wj=w&3) owns rows [wr*128, +128), j [wj*16, +16), all 4 gates.
__global__ __launch_bounds__(512, 2) void slstm_main(
    const u16* __restrict__ xb, const u16* __restrict__ hb, const u16* __restrict__ Wt,
    const float* __restrict__ b_i, const float* __restrict__ b_h,
    const float* __restrict__ c_in, const float* __restrict__ m_in, const float* __restrict__ n_in,
    float* __restrict__ out)
{
  extern __shared__ __align__(16) u16 lds[];   // 128KB: As[2][16384] | Bs[2][16384]

  const int tid = threadIdx.x, lane = tid & 63, w = tid >> 6;

  // XCD-aware swizzle (512%8==0, bijective): XCD gets 4 row-blocks x 16 j-panels
  const int d = blockIdx.x;
  const int xcd = d & 7, loc = d >> 3;                 // 64 blocks per XCD
  const int row_blk = (xcd & 3) * 4 + (loc & 3);       // 0..15
  const int j_blk   = (xcd >> 2) * 16 + (loc >> 2);    // 0..31
  const int row0 = row_blk * 256;
  const int j0   = j_blk * 64;
  const int jh   = (j0 >= 1024) ? 1 : 0;

  const int l3 = lane >> 3, l7 = lane & 7, l15 = lane & 15, l4 = lane >> 4;
  const int kcS = l7 ^ l3;          // pre-swizzled source k-chunk (staging)
  const int wr = w >> 2, wj = w & 3;

  // staging global source offsets (u16 units); per-step deltas added in macros
  const size_t aoffx = (size_t)(row0 + w * 32 + l3) * 1024 + kcS * 8;
  const size_t aoffh = (size_t)(row0 + w * 32 + l3) * 2048 + kcS * 8;
  const size_t boffx = (size_t)((w >> 1) * 2048 + j0 + (w & 1) * 32 + l3) * 1280 + kcS * 8;
  const size_t boffh = (size_t)(j0 + w * 8 + l3) * 1280 + 1024 + kcS * 8;
  // staging LDS dest bases (u16 units, wave-uniform)
  const int aDst  = w * 2048;                       // + i*512
  const int bDstx = (w >> 1) * 4096 + (w & 1) * 2048;  // + i*512
  const int bDsth = w * 512;                        // + q*4096

  // fragment read offsets (swizzled); ^32 flips to k-slice s=1
  const int sw8 = (l4 ^ l7) << 3;
  const int aRd = (wr * 128 + l15) * 64 + sw8;      // + f*1024
  const int bRd = (wj * 16 + l15) * 64 + sw8;       // + q*4096

  f32x4 acc[4][8];
  #pragma unroll
  for (int q = 0; q < 4; ++q)
    #pragma unroll
    for (int f = 0; f < 8; ++f)
      acc[q][f] = f32x4{0.0f, 0.0f, 0.0f, 0.0f};

#define AS(PB) (lds + (PB) * 16384)
#define BS(PB) (lds + 32768 + (PB) * 16384)

#define STAGE_X(T, PB) do { \
    const u16* ax_ = xb + aoffx + (T) * 64; \
    u16* Ad_ = AS(PB); \
    _Pragma("unroll") for (int i_ = 0; i_ < 4; ++i_) gll16(ax_ + i_ * 8192, Ad_ + aDst + i_ * 512); \
    const u16* bx_ = Wt + boffx + (T) * 64; \
    u16* Bd_ = BS(PB); \
    _Pragma("unroll") for (int i_ = 0; i_ < 4; ++i_) gll16(bx_ + i_ * 10240, Bd_ + bDstx + i_ * 512); \
  } while (0)

#define STAGE_H(Q, KK, PB) do { \
    const u16* ah_ = hb + aoffh + (2 * (Q) + jh) * 256 + (KK); \
    u16* Ad_ = AS(PB); \
    _Pragma("unroll") for (int i_ = 0; i_ < 4; ++i_) gll16(ah_ + i_ * 16384, Ad_ + aDst + i_ * 512); \
    gll16(Wt + boffh + (size_t)(Q) * 2621440 + (KK), BS(PB) + (Q) * 4096 + bDsth); \
  } while (0)

#define COMPUTE_X(PB) do { \
    const u16* A_ = AS(PB); const u16* B_ = BS(PB); \
    _Pragma("unroll") for (int s_ = 0; s_ < 2; ++s_) { \
      const int sx_ = s_ * 32; \
      bf16x8 a_[8], b_[4]; \
      _Pragma("unroll") for (int f_ = 0; f_ < 8; ++f_) \
        a_[f_] = *(const bf16x8*)(A_ + ((aRd + f_ * 1024) ^ sx_)); \
      _Pragma("unroll") for (int q_ = 0; q_ < 4; ++q_) \
        b_[q_] = *(const bf16x8*)(B_ + q_ * 4096 + (bRd ^ sx_)); \
      __builtin_amdgcn_s_setprio(1); \
      _Pragma("unroll") for (int q_ = 0; q_ < 4; ++q_) \
        _Pragma("unroll") for (int f_ = 0; f_ < 8; ++f_) \
          acc[q_][f_] = __builtin_amdgcn_mfma_f32_16x16x32_bf16(a_[f_], b_[q_], acc[q_][f_], 0, 0, 0); \
      __builtin_amdgcn_s_setprio(0); \
    } \
  } while (0)

#define COMPUTE_H(QC, PB) do { \
    const u16* A_ = AS(PB); const u16* B_ = BS(PB); \
    _Pragma("unroll") for (int s_ = 0; s_ < 2; ++s_) { \
      const int sx_ = s_ * 32; \
      bf16x8 a_[8]; \
      _Pragma("unroll") for (int f_ = 0; f_ < 8; ++f_) \
        a_[f_] = *(const bf16x8*)(A_ + ((aRd + f_ * 1024) ^ sx_)); \
      bf16x8 b_ = *(const bf16x8*)(B_ + (QC) * 4096 + (bRd ^ sx_)); \
      __builtin_amdgcn_s_setprio(1); \
      _Pragma("unroll") for (int f_ = 0; f_ < 8; ++f_) \
        acc[QC][f_] = __builtin_amdgcn_mfma_f32_16x16x32_bf16(a_[f_], b_, acc[QC][f_], 0, 0, 0); \
      __builtin_amdgcn_s_setprio(0); \
    } \
  } while (0)

  // ---- pipeline: 16 x-steps then 16 h-steps, prefetch depth 1 ----
  STAGE_X(0, 0);
  __syncthreads();
  for (int t = 0; t < 16; ++t) {
    if (t < 15) { STAGE_X(t + 1, (t + 1) & 1); }
    else        { STAGE_H(0, 0, 0); }          // global step 16 -> buf 0
    COMPUTE_X(t & 1);
    __syncthreads();
  }
  #pragma unroll
  for (int th = 0; th < 16; ++th) {
    if (th < 15) {
      const int tn = th + 1;
      STAGE_H(tn >> 2, (tn & 3) * 64, tn & 1);
    }
    const int q_ = th >> 2;
    if      (q_ == 0) COMPUTE_H(0, th & 1);
    else if (q_ == 1) COMPUTE_H(1, th & 1);
    else if (q_ == 2) COMPUTE_H(2, th & 1);
    else              COMPUTE_H(3, th & 1);
    if (th < 15) __syncthreads();
  }

  // ---- epilogue: gates + state update ----
  // C layout (16x16x32): col = lane&15, row = (lane>>4)*4 + reg
  const int gj = j0 + wj * 16 + l15;
  const float bias0 = b_i[gj]        + b_h[gj];
  const float bias1 = b_i[2048 + gj] + b_h[2048 + gj];
  const float bias2 = b_i[4096 + gj] + b_h[4096 + gj];
  const float bias3 = b_i[6144 + gj] + b_h[6144 + gj];
  #pragma unroll
  for (int f = 0; f < 8; ++f) {
    #pragma unroll
    for (int r = 0; r < 4; ++r) {
      const int gb = row0 + wr * 128 + f * 16 + l4 * 4 + r;
      const size_t idx = (size_t)gb * 2048 + gj;
      const float it = acc[0][f][r] + bias0;
      const float ft = acc[1][f][r] + bias1;
      const float zt = acc[2][f][r] + bias2;
      const float ot = acc[3][f][r] + bias3;
      const float mv = m_in[idx], cv = c_in[idx], nv = n_in[idx];
      const float mn = fmaxf(ft + mv, it);
      const float iv = __expf(it - mn);
      const float fv = __expf(ft - mn + mv);
      const float az = fabsf(zt);
      const float e2 = __expf(-2.0f * az);
      const float tz = (1.0f - e2) / (1.0f + e2);
      const float zv = (zt >= 0.0f) ? tz : -tz;
      const float ov = 1.0f / (1.0f + __expf(-ot));
      const float cn = fv * cv + iv * zv;
      const float nn = fv * nv + iv;
      const float hn = ov * (cn / nn);
      out[idx]            = hn;
      out[ 8388608 + idx] = cn;
      out[16777216 + idx] = mn;
      out[25165824 + idx] = nn;
    }
  }
#undef AS
#undef BS
#undef STAGE_X
#undef STAGE_H
#undef COMPUTE_X
#undef COMPUTE_H
}

extern "C" void kernel_launch(void* const* d_in, const int* in_sizes, int n_in,
                              void* d_out, int out_size, void* d_ws, size_t ws_size,
                              hipStream_t stream) {
  (void)in_sizes; (void)n_in; (void)out_size; (void)ws_size;
  const float* x  = (const float*)d_in[0];
  const float* h  = (const float*)d_in[1];
  const float* c  = (const float*)d_in[2];
  const float* m  = (const float*)d_in[3];
  const float* n  = (const float*)d_in[4];
  const float* Wi = (const float*)d_in[5];
  const float* bi = (const float*)d_in[6];
  const float* Wh = (const float*)d_in[7];
  const float* bh = (const float*)d_in[8];
  float* out = (float*)d_out;

  // workspace (bf16): WpackT 8192x1280 | xb 4096x1024 | hb 4096x2048 (~45MB)
  u16* Wt = (u16*)d_ws;
  u16* xb = Wt + (size_t)8192 * 1280;
  u16* hb = xb + (size_t)4096 * 1024;

  static_assert(sizeof(u16) == 2, "");
  hipFuncSetAttribute((const void*)slstm_main,
                      hipFuncAttributeMaxDynamicSharedMemorySize, 131072);

  cast_bf16_kernel<<<2048, 256, 0, stream>>>(x, xb, 4096 * 1024 / 8);
  cast_bf16_kernel<<<4096, 256, 0, stream>>>(h, hb, 4096 * 2048 / 8);
  pack_w_kernel<<<dim3(128, 20), dim3(64, 16), 0, stream>>>(Wi, Wh, Wt);
  slstm_main<<<512, 512, 131072, stream>>>(xb, hb, Wt, bi, bh, c, m, n, out);
}

// Round 3
// 168.171 us; speedup vs baseline: 1.3668x; 1.0334x over previous
//
#include <hip/hip_runtime.h>
#include <cstdint>
#include <cstddef>

// SLSTM cell, B=4096 IN=1024 HID=2048 GATE=8192, NH=8 HS=256.
// v3: m201-style counted-vmcnt phase schedule. 256x(64j x 4gate) tile, BK=64,
// double-buffered x-LDS (128KB) in 4 half-tiles/K-tile, one half prefetched per
// phase, s_waitcnt vmcnt(6) (never 0) + raw s_barrier; h-phase triple-buffered
// (3x40KB) with vmcnt(5)/step. Static issue/wait ledger, hand-verified.

typedef unsigned short u16;
typedef unsigned int   u32;
typedef __bf16 bf16x8 __attribute__((ext_vector_type(8)));
typedef float  f32x4  __attribute__((ext_vector_type(4)));

__device__ __forceinline__ u16 f2bf(float f) {
  u32 u = __builtin_bit_cast(u32, f);
  u32 r = (u + 0x7fffu + ((u >> 16) & 1u)) >> 16;   // RNE
  return (u16)r;
}

__device__ __forceinline__ void gll16(const void* g, void* l) {
  __builtin_amdgcn_global_load_lds(
      (__attribute__((address_space(1))) void*)(uintptr_t)g,
      (__attribute__((address_space(3))) void*)l, 16, 0, 0);
}

// ---------------- cast f32 -> bf16, 8 elems/thread ----------------
__global__ void cast_bf16_kernel(const float* __restrict__ src, u16* __restrict__ dst, int n8) {
  int i = blockIdx.x * blockDim.x + threadIdx.x;
  if (i >= n8) return;
  const float4* s = reinterpret_cast<const float4*>(src) + (size_t)i * 2;
  float4 a = s[0], b = s[1];
  union { u16 h[8]; uint4 v; } o;
  o.h[0] = f2bf(a.x); o.h[1] = f2bf(a.y); o.h[2] = f2bf(a.z); o.h[3] = f2bf(a.w);
  o.h[4] = f2bf(b.x); o.h[5] = f2bf(b.y); o.h[6] = f2bf(b.z); o.h[7] = f2bf(b.w);
  reinterpret_cast<uint4*>(dst)[i] = o.v;
}

// ---------------- pack W transposed: WpackT[g][r], g<8192, r<1280 ----------------
__global__ void pack_w_kernel(const float* __restrict__ Wi, const float* __restrict__ Wh,
                              u16* __restrict__ Wt) {
  __shared__ u16 tile[64][65];
  const int g0 = blockIdx.x * 64;
  const int r0 = blockIdx.y * 64;
  const int tx = threadIdx.x;
  const int ty = threadIdx.y;
  #pragma unroll
  for (int i = 0; i < 4; ++i) {
    const int rr = ty + 16 * i;
    const int r = r0 + rr;
    const int g = g0 + tx;
    float v;
    if (r < 1024) v = Wi[(size_t)r * 8192 + g];
    else {
      const int head = g >> 10;
      v = Wh[(size_t)(head * 256 + (r - 1024)) * 1024 + (g & 1023)];
    }
    tile[rr][tx] = f2bf(v);
  }
  __syncthreads();
  #pragma unroll
  for (int i = 0; i < 4; ++i) {
    const int gg = ty + 16 * i;
    Wt[(size_t)(g0 + gg) * 1280 + r0 + tx] = tile[tx][gg];
  }
}

// ---------------- fused GEMM (K=1280) + gate epilogue ----------------
__global__ __launch_bounds__(512, 1) void slstm_main(
    const u16* __restrict__ xb, const u16* __restrict__ hb, const u16* __restrict__ Wt,
    const float* __restrict__ b_i, const float* __restrict__ b_h,
    const float* __restrict__ c_in, const float* __restrict__ m_in, const float* __restrict__ n_in,
    float* __restrict__ out)
{
  extern __shared__ __align__(16) u16 lds[];  // 131072 B
  // x layout (u16 units): A(b) = b*16384 [A-X 8192 | A-Y 8192]; B(b) = 32768 + b*16384
  // h layout: hbuf(j) = j*20480 [A 16384 | B 4096], j=0..2

  const int tid = threadIdx.x, lane = tid & 63, w = tid >> 6;
  const int wr = w >> 2, wj = w & 3;

  // bijective XCD-aware swizzle: 512 blocks, 64/XCD
  const int d = blockIdx.x;
  const int xcd = d & 7, loc = d >> 3;
  const int row_blk = (xcd & 3) * 4 + (loc & 3);       // 0..15
  const int j_blk   = (xcd >> 2) * 16 + (loc >> 2);    // 0..31
  const int row0 = row_blk * 256;
  const int j0   = j_blk * 64;
  const int jh   = (j0 >= 1024) ? 1 : 0;

  const int l15 = lane & 15, l4 = lane >> 4, k7 = lane & 7;
  const int swz0 = (l4 ^ k7) << 3;
  const int swz1 = swz0 ^ 32;

  // ---- per-lane staging constants ----
  const int u0 = w * 64 + lane;          // load unit i=0 (0..511)
  const int u1 = 512 + u0;               // i=1
  const int u2 = 1024 + u0, u3 = 1536 + u0;
  const int r0u = u0 >> 3, r1u = u1 >> 3, r2u = u2 >> 3, r3u = u3 >> 3;
  const int kc0 = (u0 & 7) ^ (r0u & 7);
  const int kc1 = (u1 & 7) ^ (r1u & 7);
  const int kc2 = (u2 & 7) ^ (r2u & 7);
  const int kc3 = (u3 & 7) ^ (r3u & 7);
  // x A halves: A-X rows {0..63,128..191}, A-Y = +64
  const size_t aS00 = (size_t)(row0 + (r0u < 64 ? r0u : r0u + 64)) * 1024 + kc0 * 8;
  const size_t aS01 = (size_t)(row0 + (r1u < 64 ? r1u : r1u + 64)) * 1024 + kc1 * 8;
  const size_t aS10 = aS00 + 65536;
  const size_t aS11 = aS01 + 65536;
  const int aD0 = u0 * 8, aD1 = u1 * 8;
  // x B halves: B-X gates 0,1; B-Y gates 2,3
  const size_t bS00 = (size_t)((r0u >> 6) * 2048 + j0 + (r0u & 63)) * 1280 + kc0 * 8;
  const size_t bS01 = (size_t)((r1u >> 6) * 2048 + j0 + (r1u & 63)) * 1280 + kc1 * 8;
  const size_t bS10 = bS00 + (size_t)2 * 2048 * 1280;
  const size_t bS11 = bS01 + (size_t)2 * 2048 * 1280;
  // h A (4 loads, rows 0..255), h B (1 load, 64 cols)
  const size_t hA0 = (size_t)(row0 + r0u) * 2048 + kc0 * 8;
  const size_t hA1 = (size_t)(row0 + r1u) * 2048 + kc1 * 8;
  const size_t hA2 = (size_t)(row0 + r2u) * 2048 + kc2 * 8;
  const size_t hA3 = (size_t)(row0 + r3u) * 2048 + kc3 * 8;
  const int hAD0 = u0 * 8, hAD1 = u1 * 8, hAD2 = u2 * 8, hAD3 = u3 * 8;
  const size_t hBS = (size_t)(j0 + r0u) * 1280 + 1024 + kc0 * 8;
  const int hBD = 16384 + u0 * 8;
  // read bases
  const int aRdR = (wr * 64 + l15) * 64;
  const int bRdC = (wj * 16 + l15) * 64;
  const int hRdR = (wr * 128 + l15) * 64;
  const int hRdC = 16384 + bRdC;

  f32x4 acc[4][8];
  #pragma unroll
  for (int q = 0; q < 4; ++q)
    #pragma unroll
    for (int f = 0; f < 8; ++f)
      acc[q][f] = f32x4{0.0f, 0.0f, 0.0f, 0.0f};

#define BAR() asm volatile("s_barrier" ::: "memory")
#define WAITV(N) asm volatile("s_waitcnt vmcnt(" #N ")" ::: "memory")

#define ST_AX(TN, NB) do { \
    gll16(xb + aS00 + (size_t)(TN) * 64, lds + (NB) * 16384 + aD0); \
    gll16(xb + aS01 + (size_t)(TN) * 64, lds + (NB) * 16384 + aD1); } while (0)
#define ST_AY(TN, NB) do { \
    gll16(xb + aS10 + (size_t)(TN) * 64, lds + (NB) * 16384 + 8192 + aD0); \
    gll16(xb + aS11 + (size_t)(TN) * 64, lds + (NB) * 16384 + 8192 + aD1); } while (0)
#define ST_BX(TN, NB) do { \
    gll16(Wt + bS00 + (size_t)(TN) * 64, lds + 32768 + (NB) * 16384 + aD0); \
    gll16(Wt + bS01 + (size_t)(TN) * 64, lds + 32768 + (NB) * 16384 + aD1); } while (0)
#define ST_BY(TN, NB) do { \
    gll16(Wt + bS10 + (size_t)(TN) * 64, lds + 32768 + (NB) * 16384 + 8192 + aD0); \
    gll16(Wt + bS11 + (size_t)(TN) * 64, lds + 32768 + (NB) * 16384 + 8192 + aD1); } while (0)

#define READ_A(DST, B_, HOFF) do { \
    const u16* p_ = lds + (B_) * 16384 + (HOFF) + aRdR; \
    _Pragma("unroll") for (int f_ = 0; f_ < 4; ++f_) { \
      DST[f_ * 2]     = *(const bf16x8*)(p_ + f_ * 1024 + swz0); \
      DST[f_ * 2 + 1] = *(const bf16x8*)(p_ + f_ * 1024 + swz1); } } while (0)
#define READ_B(DST, B_, HOFF) do { \
    const u16* p_ = lds + 32768 + (B_) * 16384 + (HOFF) + bRdC; \
    _Pragma("unroll") for (int q_ = 0; q_ < 2; ++q_) { \
      DST[q_ * 2]     = *(const bf16x8*)(p_ + q_ * 4096 + swz0); \
      DST[q_ * 2 + 1] = *(const bf16x8*)(p_ + q_ * 4096 + swz1); } } while (0)

#define MM(AV, BV, F0, Q0) do { \
    __builtin_amdgcn_s_setprio(1); \
    _Pragma("unroll") for (int q_ = 0; q_ < 2; ++q_) \
      _Pragma("unroll") for (int f_ = 0; f_ < 4; ++f_) \
        _Pragma("unroll") for (int s_ = 0; s_ < 2; ++s_) \
          acc[(Q0) + q_][(F0) + f_] = __builtin_amdgcn_mfma_f32_16x16x32_bf16( \
              AV[f_ * 2 + s_], BV[q_ * 2 + s_], acc[(Q0) + q_][(F0) + f_], 0, 0, 0); \
    __builtin_amdgcn_s_setprio(0); } while (0)

// one x K-tile: 4 phases, issue next tile's halves in first-use order
#define XTILE(T, B, NB) do { \
    bf16x8 alo[8], blo[4], bhi[4], ahi[8]; \
    ST_AX((T) + 1, NB); WAITV(6); BAR(); \
    READ_A(alo, B, 0); READ_B(blo, B, 0); \
    MM(alo, blo, 0, 0); \
    ST_BX((T) + 1, NB); WAITV(6); BAR(); \
    READ_B(bhi, B, 8192); \
    MM(alo, bhi, 0, 2); \
    ST_BY((T) + 1, NB); WAITV(6); BAR(); \
    READ_A(ahi, B, 8192); \
    MM(ahi, blo, 4, 0); \
    ST_AY((T) + 1, NB); BAR(); \
    MM(ahi, bhi, 4, 2); \
  } while (0)

  // ---- prologue: tile0's 4 halves in first-use order ----
  ST_AX(0, 0); ST_BX(0, 0); ST_BY(0, 0); ST_AY(0, 0);

  // ---- x-phase tiles 0..14 ----
  for (int tt = 0; tt < 7; ++tt) {
    XTILE(2 * tt, 0, 1);
    XTILE(2 * tt + 1, 1, 0);
  }
  XTILE(14, 0, 1);

  // ---- tile 15 (buf 1): issue h-step0's 5 loads across its phases ----
  {
    bf16x8 alo[8], blo[4], bhi[4], ahi[8];
    gll16(hb + hA0 + jh * 256, lds + hAD0);       // h0.A loads 0-1 -> hbuf0
    gll16(hb + hA1 + jh * 256, lds + hAD1);
    WAITV(6); BAR();
    READ_A(alo, 1, 0); READ_B(blo, 1, 0);
    MM(alo, blo, 0, 0);
    gll16(hb + hA2 + jh * 256, lds + hAD2);       // h0.A loads 2-3
    gll16(hb + hA3 + jh * 256, lds + hAD3);
    WAITV(6); BAR();
    READ_B(bhi, 1, 8192);
    MM(alo, bhi, 0, 2);
    gll16(Wt + hBS, lds + hBD);                   // h0.B
    WAITV(5); BAR();
    READ_A(ahi, 1, 8192);
    MM(ahi, blo, 4, 0);
    BAR();
    MM(ahi, bhi, 4, 2);
  }

  // ---- h-steps 0..15 (triple-buffered, vmcnt(5) per step) ----
  #pragma unroll
  for (int uu = 0; uu < 16; ++uu) {
    const int jb = uu % 3;
    const int q = uu >> 2;
    if (uu < 15) {
      const int v = uu + 1, jn = v % 3, qv = v >> 2, kkv = (v & 3) * 64;
      const size_t ho = (size_t)(2 * qv + jh) * 256 + kkv;
      gll16(hb + hA0 + ho, lds + jn * 20480 + hAD0);
      gll16(hb + hA1 + ho, lds + jn * 20480 + hAD1);
      gll16(hb + hA2 + ho, lds + jn * 20480 + hAD2);
      gll16(hb + hA3 + ho, lds + jn * 20480 + hAD3);
      gll16(Wt + hBS + (size_t)qv * 2621440 + kkv, lds + jn * 20480 + hBD);
      WAITV(5);
    } else {
      WAITV(0);
    }
    BAR();
    bf16x8 ha[16], hbf[2];
    {
      const u16* p_ = lds + jb * 20480 + hRdR;
      #pragma unroll
      for (int f_ = 0; f_ < 8; ++f_) {
        ha[f_ * 2]     = *(const bf16x8*)(p_ + f_ * 1024 + swz0);
        ha[f_ * 2 + 1] = *(const bf16x8*)(p_ + f_ * 1024 + swz1);
      }
      const u16* pb_ = lds + jb * 20480 + hRdC;
      hbf[0] = *(const bf16x8*)(pb_ + swz0);
      hbf[1] = *(const bf16x8*)(pb_ + swz1);
    }
    __builtin_amdgcn_s_setprio(1);
    #pragma unroll
    for (int f_ = 0; f_ < 8; ++f_)
      #pragma unroll
      for (int s_ = 0; s_ < 2; ++s_)
        acc[q][f_] = __builtin_amdgcn_mfma_f32_16x16x32_bf16(ha[f_ * 2 + s_], hbf[s_], acc[q][f_], 0, 0, 0);
    __builtin_amdgcn_s_setprio(0);
  }

  // ---- epilogue: gates + state update ----
  // C layout (16x16x32): col = lane&15, row = (lane>>4)*4 + reg
  const int gj = j0 + wj * 16 + l15;
  const float bias0 = b_i[gj]        + b_h[gj];
  const float bias1 = b_i[2048 + gj] + b_h[2048 + gj];
  const float bias2 = b_i[4096 + gj] + b_h[4096 + gj];
  const float bias3 = b_i[6144 + gj] + b_h[6144 + gj];
  #pragma unroll
  for (int f = 0; f < 8; ++f) {
    #pragma unroll
    for (int r = 0; r < 4; ++r) {
      const int gb = row0 + wr * 128 + f * 16 + l4 * 4 + r;
      const size_t idx = (size_t)gb * 2048 + gj;
      const float it = acc[0][f][r] + bias0;
      const float ft = acc[1][f][r] + bias1;
      const float zt = acc[2][f][r] + bias2;
      const float ot = acc[3][f][r] + bias3;
      const float mv = m_in[idx], cv = c_in[idx], nv = n_in[idx];
      const float mn = fmaxf(ft + mv, it);
      const float iv = __expf(it - mn);
      const float fv = __expf(ft - mn + mv);
      const float az = fabsf(zt);
      const float e2 = __expf(-2.0f * az);
      const float tz = (1.0f - e2) / (1.0f + e2);
      const float zv = (zt >= 0.0f) ? tz : -tz;
      const float ov = 1.0f / (1.0f + __expf(-ot));
      const float cn = fv * cv + iv * zv;
      const float nn = fv * nv + iv;
      const float hn = ov * (cn / nn);
      out[idx]            = hn;
      out[ 8388608 + idx] = cn;
      out[16777216 + idx] = mn;
      out[25165824 + idx] = nn;
    }
  }
#undef BAR
#undef WAITV
#undef ST_AX
#undef ST_AY
#undef ST_BX
#undef ST_BY
#undef READ_A
#undef READ_B
#undef MM
#undef XTILE
}

extern "C" void kernel_launch(void* const* d_in, const int* in_sizes, int n_in,
                              void* d_out, int out_size, void* d_ws, size_t ws_size,
                              hipStream_t stream) {
  (void)in_sizes; (void)n_in; (void)out_size; (void)ws_size;
  const float* x  = (const float*)d_in[0];
  const float* h  = (const float*)d_in[1];
  const float* c  = (const float*)d_in[2];
  const float* m  = (const float*)d_in[3];
  const float* n  = (const float*)d_in[4];
  const float* Wi = (const float*)d_in[5];
  const float* bi = (const float*)d_in[6];
  const float* Wh = (const float*)d_in[7];
  const float* bh = (const float*)d_in[8];
  float* out = (float*)d_out;

  // workspace (bf16): WpackT 8192x1280 | xb 4096x1024 | hb 4096x2048 (~45MB)
  u16* Wt = (u16*)d_ws;
  u16* xb = Wt + (size_t)8192 * 1280;
  u16* hb = xb + (size_t)4096 * 1024;

  hipFuncSetAttribute((const void*)slstm_main,
                      hipFuncAttributeMaxDynamicSharedMemorySize, 131072);

  cast_bf16_kernel<<<2048, 256, 0, stream>>>(x, xb, 4096 * 1024 / 8);
  cast_bf16_kernel<<<4096, 256, 0, stream>>>(h, hb, 4096 * 2048 / 8);
  pack_w_kernel<<<dim3(128, 20), dim3(64, 16), 0, stream>>>(Wi, Wh, Wt);
  slstm_main<<<512, 512, 131072, stream>>>(xb, hb, Wt, bi, bh, c, m, n, out);
}